// Round 6
// baseline (319.329 us; speedup 1.0000x reference)
//
#include <hip/hip_runtime.h>
#include <hip/hip_bf16.h>

#define H 128
#define CAP 48
#define CSTRIDE 16   // one counter per 64B sector

typedef _Float16 f16x4 __attribute__((ext_vector_type(4)));
typedef _Float16 f16x8 __attribute__((ext_vector_type(8)));
typedef float    f32x4 __attribute__((ext_vector_type(4)));
typedef float    f32x2 __attribute__((ext_vector_type(2)));

__device__ __forceinline__ float silu_f(float v) {
    return v / (1.0f + __expf(-v));
}

// ---------------------------------------------------------------------------
// Weight pre-pack: 10 matrices [128k][128c] f32 -> fp16 A-frag layout,
// plus e_w [32k][128c] -> fp16 B-frag layout (8 col-tiles, 512 threads).
// Also zeroes the padded (40960*CSTRIDE) bucket-count array.
// ---------------------------------------------------------------------------
__global__ __launch_bounds__(256)
void pack_w(const float* __restrict__ emb_w, const float* __restrict__ conv_w,
            const float* __restrict__ out_w, const float* __restrict__ e_w,
            _Float16* __restrict__ wpk, int* __restrict__ cnt)
{
    const int gid = blockIdx.x * 256 + threadIdx.x;     // 20992 = 82*256

    // zero padded counters (coalesced, all threads)
#pragma unroll
    for (int i = 0; i < 32; ++i) {
        const int idx = gid + i * 20992;
        if (idx < 40960 * CSTRIDE) cnt[idx] = 0;
    }

    _Float16* dst = wpk + (size_t)gid * 8;
    if (gid < 20480) {
        const int mat = gid >> 11;
        const int r   = gid & 2047;
        const int ct  = r >> 8;
        const int kb  = (r >> 6) & 3;
        const int lane = r & 63;
        const float* W = (mat < 4) ? emb_w + mat * 16384
                       : (mat < 8) ? conv_w + (mat - 4) * 16384
                                   : out_w + (mat - 8) * 16384;
        const int m  = ct * 16 + (lane & 15);
        const int k0 = kb * 32 + (lane >> 4) * 8;
#pragma unroll
        for (int j = 0; j < 8; ++j)
            dst[j] = (_Float16)W[(k0 + j) * H + m];
    } else {
        const int r    = gid - 20480;                   // 0..511
        const int ct   = r >> 6;
        const int lane = r & 63;
        const int m    = ct * 16 + (lane & 15);
        const int k0   = (lane >> 4) * 8;
#pragma unroll
        for (int j = 0; j < 8; ++j)
            dst[j] = (_Float16)e_w[(k0 + j) * H + m];
    }
}

// ---------------------------------------------------------------------------
// MFMA helpers. CT = 16-col tiles per wave, ct0 = wave's first tile.
// ---------------------------------------------------------------------------
template <int CT>
__device__ __forceinline__ void mfma_layerT(const _Float16* __restrict__ w,
                                            const f16x8 bf[4], int ct0, int lane,
                                            f32x4 acc[CT])
{
#pragma unroll
    for (int c = 0; c < CT; ++c) acc[c] = (f32x4){0.f, 0.f, 0.f, 0.f};
#pragma unroll
    for (int kb = 0; kb < 4; ++kb) {
#pragma unroll
        for (int ctl = 0; ctl < CT; ++ctl) {
            f16x8 af = *(const f16x8*)(w + ((size_t)((ct0 + ctl) * 4 + kb) * 64 + lane) * 8);
            acc[ctl] = __builtin_amdgcn_mfma_f32_16x16x32_f16(af, bf[kb], acc[ctl], 0, 0, 0);
        }
    }
}

template <int CT>
__device__ __forceinline__ void store_stripT(_Float16* strip, const f32x4 acc[CT],
                                             const float* bias, int ct0, int rl, int quad)
{
#pragma unroll
    for (int ctl = 0; ctl < CT; ++ctl) {
        const int c = (ct0 + ctl) * 16 + quad * 4;
        float4 bb = *(const float4*)(bias + c);
        f16x4 hv = {(_Float16)silu_f(acc[ctl][0] + bb.x),
                    (_Float16)silu_f(acc[ctl][1] + bb.y),
                    (_Float16)silu_f(acc[ctl][2] + bb.z),
                    (_Float16)silu_f(acc[ctl][3] + bb.w)};
        *(f16x4*)(strip + rl * 136 + c) = hv;
    }
}

template <int CT>
__device__ __forceinline__ void store_strip_rawT(_Float16* strip, const f32x4 t[CT],
                                                 int ct0, int rl, int quad)
{
#pragma unroll
    for (int ctl = 0; ctl < CT; ++ctl) {
        const int c = (ct0 + ctl) * 16 + quad * 4;
        f16x4 hv = {(_Float16)t[ctl][0], (_Float16)t[ctl][1],
                    (_Float16)t[ctl][2], (_Float16)t[ctl][3]};
        *(f16x4*)(strip + rl * 136 + c) = hv;
    }
}

__device__ __forceinline__ void load_bf(const _Float16* strip, f16x8 bf[4],
                                        int rl, int quad)
{
#pragma unroll
    for (int kb = 0; kb < 4; ++kb)
        bf[kb] = *(const f16x8*)(strip + rl * 136 + kb * 32 + quad * 8);
}

// ---------------------------------------------------------------------------
// embscat_k: INTERLEAVED horizontal fusion (blockIdx&1) so scatter blocks
// (latency/atomic-bound) co-reside with emb2 blocks (MFMA-bound):
//   odd blocks : bucket scatter — one atomic pass builds per-node edge lists,
//                4-byte packed entries: (e_local<<14)|col
//   even blocks: emb2 — s2s = mlp2(x; mats 0,1), sdst = mlp2(x; 2,3)
// ---------------------------------------------------------------------------
__global__ __launch_bounds__(256)
void embscat_k(const float* __restrict__ x, const _Float16* __restrict__ wpk,
               const float* __restrict__ emb_b,
               float* __restrict__ s2s, float* __restrict__ sdst,
               const int* __restrict__ eidx, int* __restrict__ cnt,
               unsigned* __restrict__ bucket)
{
    __shared__ _Float16 hsA[16 * 136], hsB[16 * 136];

    if (blockIdx.x & 1) {
        // ---- bucket scatter ----
        const int e = (blockIdx.x >> 1) * 256 + threadIdx.x;   // 640000 exact
        const int2 rc = ((const int2*)eidx)[e];
        const int b = (unsigned)e / 160000u;
        const int key = b * 10000 + rc.x;
        const int pos = atomicAdd(&cnt[key * CSTRIDE], 1);
        if (pos < CAP)
            bucket[(size_t)key * CAP + pos] =
                ((unsigned)(e - b * 160000) << 14) | (unsigned)rc.y;
        return;
    }

    // ---- emb2 part ----
    const int bid  = blockIdx.x >> 1;
    const int tid  = threadIdx.x;
    const int lane = tid & 63;
    const int wid  = tid >> 6;
    const int half = wid & 1;
    const int msel = wid >> 1;
    const int rl   = lane & 15;
    const int quad = lane >> 4;
    const int row  = bid * 16 + rl;
    const size_t rbase = (size_t)row * H;

    f16x8 bf[4];
#pragma unroll
    for (int kb = 0; kb < 4; ++kb) {
        const int kc = kb * 32 + quad * 8;
        float4 v0 = *(const float4*)(x + rbase + kc);
        float4 v1 = *(const float4*)(x + rbase + kc + 4);
        bf[kb] = (f16x8){(_Float16)v0.x, (_Float16)v0.y, (_Float16)v0.z, (_Float16)v0.w,
                         (_Float16)v1.x, (_Float16)v1.y, (_Float16)v1.z, (_Float16)v1.w};
    }

    const _Float16* wm = wpk + (size_t)msel * 2 * 16384;
    _Float16* strip = msel ? hsB : hsA;
    const float* bias0 = emb_b + msel * 2 * H;

    f32x4 acc[4];
    mfma_layerT<4>(wm, bf, half * 4, lane, acc);
    store_stripT<4>(strip, acc, bias0, half * 4, rl, quad);
    __syncthreads();
    load_bf(strip, bf, rl, quad);
    mfma_layerT<4>(wm + 16384, bf, half * 4, lane, acc);

    float* outp = msel ? sdst : s2s;
    const float* bias1 = bias0 + H;
#pragma unroll
    for (int ctl = 0; ctl < 4; ++ctl) {
        const int c = (half * 4 + ctl) * 16 + quad * 4;
        float4 bb = *(const float4*)(bias1 + c);
        float4 v;
        v.x = silu_f(acc[ctl][0] + bb.x);
        v.y = silu_f(acc[ctl][1] + bb.y);
        v.z = silu_f(acc[ctl][2] + bb.z);
        v.w = silu_f(acc[ctl][3] + bb.w);
        *(float4*)(outp + rbase + c) = v;
    }
}

// ---------------------------------------------------------------------------
// out6_k: fused tail — conv -> residual(conv_w0) -> residual(conv_w1)
//                      -> z = s2s .* conv -> out = z + mlp2(z; out_w)
// ---------------------------------------------------------------------------
__global__ __launch_bounds__(256)
void out6_k(const float* __restrict__ conv, const float* __restrict__ s2s,
            const _Float16* __restrict__ w6,   // mats 4..9
            const float* __restrict__ conv_b, const float* __restrict__ out_b,
            float* __restrict__ y)
{
    __shared__ _Float16 hs0[16 * 136], hs1[16 * 136];
    const int tid  = threadIdx.x;
    const int lane = tid & 63;
    const int ct0  = (tid >> 6) * 2;
    const int rl   = lane & 15;
    const int quad = lane >> 4;
    const int row  = blockIdx.x * 16 + rl;
    const size_t rbase = (size_t)row * H;

    f16x8 bf[4];
#pragma unroll
    for (int kb = 0; kb < 4; ++kb) {
        const int kc = kb * 32 + quad * 8;
        float4 v0 = *(const float4*)(conv + rbase + kc);
        float4 v1 = *(const float4*)(conv + rbase + kc + 4);
        bf[kb] = (f16x8){(_Float16)v0.x, (_Float16)v0.y, (_Float16)v0.z, (_Float16)v0.w,
                         (_Float16)v1.x, (_Float16)v1.y, (_Float16)v1.z, (_Float16)v1.w};
    }

    f32x4 acc[2], tD[2];

    mfma_layerT<2>(w6, bf, ct0, lane, acc);
    store_stripT<2>(hs0, acc, conv_b, ct0, rl, quad);
    __syncthreads();
    load_bf(hs0, bf, rl, quad);

    mfma_layerT<2>(w6 + 16384, bf, ct0, lane, acc);
#pragma unroll
    for (int ctl = 0; ctl < 2; ++ctl) {
        const int c = (ct0 + ctl) * 16 + quad * 4;
        float4 bb = *(const float4*)(conv_b + H + c);
        float4 cv = *(const float4*)(conv + rbase + c);
        tD[ctl][0] = cv.x + silu_f(acc[ctl][0] + bb.x);
        tD[ctl][1] = cv.y + silu_f(acc[ctl][1] + bb.y);
        tD[ctl][2] = cv.z + silu_f(acc[ctl][2] + bb.z);
        tD[ctl][3] = cv.w + silu_f(acc[ctl][3] + bb.w);
    }
    store_strip_rawT<2>(hs1, tD, ct0, rl, quad);
    __syncthreads();
    load_bf(hs1, bf, rl, quad);

    mfma_layerT<2>(w6 + 2 * 16384, bf, ct0, lane, acc);
    store_stripT<2>(hs0, acc, conv_b + 2 * H, ct0, rl, quad);
    __syncthreads();
    load_bf(hs0, bf, rl, quad);

    mfma_layerT<2>(w6 + 3 * 16384, bf, ct0, lane, acc);
#pragma unroll
    for (int ctl = 0; ctl < 2; ++ctl) {
        const int c = (ct0 + ctl) * 16 + quad * 4;
        float4 bb = *(const float4*)(conv_b + 3 * H + c);
        float4 sv = *(const float4*)(s2s + rbase + c);
        tD[ctl][0] = (tD[ctl][0] + silu_f(acc[ctl][0] + bb.x)) * sv.x;
        tD[ctl][1] = (tD[ctl][1] + silu_f(acc[ctl][1] + bb.y)) * sv.y;
        tD[ctl][2] = (tD[ctl][2] + silu_f(acc[ctl][2] + bb.z)) * sv.z;
        tD[ctl][3] = (tD[ctl][3] + silu_f(acc[ctl][3] + bb.w)) * sv.w;
    }
    store_strip_rawT<2>(hs1, tD, ct0, rl, quad);
    __syncthreads();
    load_bf(hs1, bf, rl, quad);

    mfma_layerT<2>(w6 + 4 * 16384, bf, ct0, lane, acc);
    store_stripT<2>(hs0, acc, out_b, ct0, rl, quad);
    __syncthreads();
    load_bf(hs0, bf, rl, quad);

    mfma_layerT<2>(w6 + 5 * 16384, bf, ct0, lane, acc);
#pragma unroll
    for (int ctl = 0; ctl < 2; ++ctl) {
        const int c = (ct0 + ctl) * 16 + quad * 4;
        float4 bb = *(const float4*)(out_b + H + c);
        float4 v;
        v.x = tD[ctl][0] + silu_f(acc[ctl][0] + bb.x);
        v.y = tD[ctl][1] + silu_f(acc[ctl][1] + bb.y);
        v.z = tD[ctl][2] + silu_f(acc[ctl][2] + bb.z);
        v.w = tD[ctl][3] + silu_f(acc[ctl][3] + bb.w);
        *(float4*)(y + rbase + c) = v;
    }
}

// ---------------------------------------------------------------------------
// Gather-reduce v10: 2 nodes per wave, fused rounds.
// Round 1: cnt[A], cnt[B] and bucket slots 0..31 of BOTH nodes load in
// parallel (unconditional; stale entries masked to 0 before any address use).
// Per tile: burst A (34 loads) + burst B (34 loads) issued back-to-back;
// vmcnt(34) -> compute A (overlaps B's latency) -> vmcnt(0) -> compute B.
// ---------------------------------------------------------------------------
#define GLD(dst, p, offlit) \
    asm volatile("global_load_dword %0, %1, off offset:" offlit \
                 : "=v"(dst) : "v"(p))
#define GLDX4(dst, p, offlit) \
    asm volatile("global_load_dwordx4 %0, %1, off offset:" offlit \
                 : "=v"(dst) : "v"(p))

__device__ __forceinline__ void tile_pair(
    const float* __restrict__ ef, const float* __restrict__ sdst,
    const f16x8 bw[8], unsigned mA, unsigned mB,
    int ebase, int srow, int quad, int el, bool okA, bool okB,
    float pA[8], float pB[8])
{
    // decode (masked entries: invalid -> edge ebase / row srow, both valid)
    const int scA0 = srow + (__shfl((int)mA, (quad << 2) | 0, 64) & 0x3FFF);
    const int scA1 = srow + (__shfl((int)mA, (quad << 2) | 1, 64) & 0x3FFF);
    const int scA2 = srow + (__shfl((int)mA, (quad << 2) | 2, 64) & 0x3FFF);
    const int scA3 = srow + (__shfl((int)mA, (quad << 2) | 3, 64) & 0x3FFF);
    const int scB0 = srow + (__shfl((int)mB, (quad << 2) | 0, 64) & 0x3FFF);
    const int scB1 = srow + (__shfl((int)mB, (quad << 2) | 1, 64) & 0x3FFF);
    const int scB2 = srow + (__shfl((int)mB, (quad << 2) | 2, 64) & 0x3FFF);
    const int scB3 = srow + (__shfl((int)mB, (quad << 2) | 3, 64) & 0x3FFF);

    const float* peA = ef + (size_t)(ebase + (int)(mA >> 14)) * 32 + (quad << 3);
    const float* peB = ef + (size_t)(ebase + (int)(mB >> 14)) * 32 + (quad << 3);
    const float* a0 = sdst + (size_t)scA0 * H + el;
    const float* a1 = sdst + (size_t)scA1 * H + el;
    const float* a2 = sdst + (size_t)scA2 * H + el;
    const float* a3 = sdst + (size_t)scA3 * H + el;
    const float* b0 = sdst + (size_t)scB0 * H + el;
    const float* b1 = sdst + (size_t)scB1 * H + el;
    const float* b2 = sdst + (size_t)scB2 * H + el;
    const float* b3 = sdst + (size_t)scB3 * H + el;

    f32x4 vA0, vA1, vB0, vB1;
    float sA0[8], sA1[8], sA2[8], sA3[8];
    float sB0[8], sB1[8], sB2[8], sB3[8];

    // ---- burst A (34) then burst B (34); volatile asm keeps issue order ----
    GLDX4(vA0, peA, "0");
    GLDX4(vA1, peA, "16");
    GLD(sA0[0], a0, "0");   GLD(sA0[1], a0, "64");  GLD(sA0[2], a0, "128");
    GLD(sA0[3], a0, "192"); GLD(sA0[4], a0, "256"); GLD(sA0[5], a0, "320");
    GLD(sA0[6], a0, "384"); GLD(sA0[7], a0, "448");
    GLD(sA1[0], a1, "0");   GLD(sA1[1], a1, "64");  GLD(sA1[2], a1, "128");
    GLD(sA1[3], a1, "192"); GLD(sA1[4], a1, "256"); GLD(sA1[5], a1, "320");
    GLD(sA1[6], a1, "384"); GLD(sA1[7], a1, "448");
    GLD(sA2[0], a2, "0");   GLD(sA2[1], a2, "64");  GLD(sA2[2], a2, "128");
    GLD(sA2[3], a2, "192"); GLD(sA2[4], a2, "256"); GLD(sA2[5], a2, "320");
    GLD(sA2[6], a2, "384"); GLD(sA2[7], a2, "448");
    GLD(sA3[0], a3, "0");   GLD(sA3[1], a3, "64");  GLD(sA3[2], a3, "128");
    GLD(sA3[3], a3, "192"); GLD(sA3[4], a3, "256"); GLD(sA3[5], a3, "320");
    GLD(sA3[6], a3, "384"); GLD(sA3[7], a3, "448");

    GLDX4(vB0, peB, "0");
    GLDX4(vB1, peB, "16");
    GLD(sB0[0], b0, "0");   GLD(sB0[1], b0, "64");  GLD(sB0[2], b0, "128");
    GLD(sB0[3], b0, "192"); GLD(sB0[4], b0, "256"); GLD(sB0[5], b0, "320");
    GLD(sB0[6], b0, "384"); GLD(sB0[7], b0, "448");
    GLD(sB1[0], b1, "0");   GLD(sB1[1], b1, "64");  GLD(sB1[2], b1, "128");
    GLD(sB1[3], b1, "192"); GLD(sB1[4], b1, "256"); GLD(sB1[5], b1, "320");
    GLD(sB1[6], b1, "384"); GLD(sB1[7], b1, "448");
    GLD(sB2[0], b2, "0");   GLD(sB2[1], b2, "64");  GLD(sB2[2], b2, "128");
    GLD(sB2[3], b2, "192"); GLD(sB2[4], b2, "256"); GLD(sB2[5], b2, "320");
    GLD(sB2[6], b2, "384"); GLD(sB2[7], b2, "448");
    GLD(sB3[0], b3, "0");   GLD(sB3[1], b3, "64");  GLD(sB3[2], b3, "128");
    GLD(sB3[3], b3, "192"); GLD(sB3[4], b3, "256"); GLD(sB3[5], b3, "320");
    GLD(sB3[6], b3, "384"); GLD(sB3[7], b3, "448");

    // wait for burst A only (B stays in flight under compute A)
    asm volatile("s_waitcnt vmcnt(34)" ::: "memory");
    __builtin_amdgcn_sched_barrier(0);

    const f16x8 afA = {
        okA ? (_Float16)vA0[0] : (_Float16)0.f, okA ? (_Float16)vA0[1] : (_Float16)0.f,
        okA ? (_Float16)vA0[2] : (_Float16)0.f, okA ? (_Float16)vA0[3] : (_Float16)0.f,
        okA ? (_Float16)vA1[0] : (_Float16)0.f, okA ? (_Float16)vA1[1] : (_Float16)0.f,
        okA ? (_Float16)vA1[2] : (_Float16)0.f, okA ? (_Float16)vA1[3] : (_Float16)0.f};
#pragma unroll
    for (int ct = 0; ct < 8; ++ct) {
        f32x4 acc = __builtin_amdgcn_mfma_f32_16x16x32_f16(
            afA, bw[ct], (f32x4){0.f, 0.f, 0.f, 0.f}, 0, 0, 0);
        pA[ct] += acc[0] * sA0[ct] + acc[1] * sA1[ct]
                + acc[2] * sA2[ct] + acc[3] * sA3[ct];
    }

    __builtin_amdgcn_sched_barrier(0);
    asm volatile("s_waitcnt vmcnt(0)" ::: "memory");
    __builtin_amdgcn_sched_barrier(0);

    const f16x8 afB = {
        okB ? (_Float16)vB0[0] : (_Float16)0.f, okB ? (_Float16)vB0[1] : (_Float16)0.f,
        okB ? (_Float16)vB0[2] : (_Float16)0.f, okB ? (_Float16)vB0[3] : (_Float16)0.f,
        okB ? (_Float16)vB1[0] : (_Float16)0.f, okB ? (_Float16)vB1[1] : (_Float16)0.f,
        okB ? (_Float16)vB1[2] : (_Float16)0.f, okB ? (_Float16)vB1[3] : (_Float16)0.f};
#pragma unroll
    for (int ct = 0; ct < 8; ++ct) {
        f32x4 acc = __builtin_amdgcn_mfma_f32_16x16x32_f16(
            afB, bw[ct], (f32x4){0.f, 0.f, 0.f, 0.f}, 0, 0, 0);
        pB[ct] += acc[0] * sB0[ct] + acc[1] * sB1[ct]
                + acc[2] * sB2[ct] + acc[3] * sB3[ct];
    }
}

__global__ __launch_bounds__(256)
void conv_k(const float* __restrict__ ef, const float* __restrict__ sdst,
            const _Float16* __restrict__ ewpk, const float* __restrict__ C,
            const int* __restrict__ cnt, const unsigned* __restrict__ bucket,
            float* __restrict__ conv)
{
    const int tid  = threadIdx.x;
    const int lane = tid & 63;
    const int el   = lane & 15;
    const int quad = lane >> 4;
    const int p    = blockIdx.x * 4 + (tid >> 6);   // 5000 blocks x 4 waves
    const int nA   = 2 * p, nB = nA + 1;            // same batch (pairs never cross)
    const int b    = (unsigned)nA / 10000u;
    const int ebase = b * 160000;
    const int srow  = b * 10000;

    const unsigned* bkA = bucket + (size_t)nA * CAP;
    const unsigned* bkB = bucket + (size_t)nB * CAP;

    // ---- round 1: counts + first 32 slots of both nodes, all in parallel ----
    const unsigned eA0 = bkA[el], eA1 = bkA[16 + el];
    const unsigned eB0 = bkB[el], eB1 = bkB[16 + el];
    const int cA = min(cnt[nA * CSTRIDE], CAP);
    const int cB = min(cnt[nB * CSTRIDE], CAP);
    const int nmax = max(cA, cB);

    f16x8 bw[8];
#pragma unroll
    for (int ct = 0; ct < 8; ++ct)
        bw[ct] = *(const f16x8*)(ewpk + ((size_t)((ct << 6) + lane)) * 8);

    float pA[8], pB[8];
#pragma unroll
    for (int ct = 0; ct < 8; ++ct) { pA[ct] = 0.f; pB[ct] = 0.f; }

    {   // tile 0 (always; n==0 handled by masks)
        const bool okA = el < cA, okB = el < cB;
        tile_pair(ef, sdst, bw, okA ? eA0 : 0u, okB ? eB0 : 0u,
                  ebase, srow, quad, el, okA, okB, pA, pB);
    }
    if (nmax > 16) {   // tile 1 (entries preloaded)
        const bool okA = el < cA - 16, okB = el < cB - 16;
        tile_pair(ef, sdst, bw, okA ? eA1 : 0u, okB ? eB1 : 0u,
                  ebase, srow, quad, el, okA, okB, pA, pB);
    }
#pragma unroll 1
    for (int base = 32; base < nmax; base += 16) {   // rare tail
        const bool okA = el < cA - base, okB = el < cB - base;
        const unsigned tA = okA ? bkA[base + el] : 0u;
        const unsigned tB = okB ? bkB[base + el] : 0u;
        tile_pair(ef, sdst, bw, tA, tB, ebase, srow, quad, el, okA, okB, pA, pB);
    }

    // cross-quad reduce, scale by C, store (both nodes)
    const float Cb = C[b];
    float w0A = 0.f, w1A = 0.f, w0B = 0.f, w1B = 0.f;
#pragma unroll
    for (int ct = 0; ct < 8; ++ct) {
        float vA = pA[ct];
        vA += __shfl_xor(vA, 16, 64);
        vA += __shfl_xor(vA, 32, 64);
        vA *= Cb;
        float vB = pB[ct];
        vB += __shfl_xor(vB, 16, 64);
        vB += __shfl_xor(vB, 32, 64);
        vB *= Cb;
        if ((ct >> 1) == quad) {
            if (ct & 1) { w1A = vA; w1B = vB; }
            else        { w0A = vA; w0B = vB; }
        }
    }
    float* dstA = conv + (size_t)nA * H + (quad << 5) + el;
    dstA[0]  = w0A;
    dstA[16] = w1A;
    float* dstB = conv + (size_t)nB * H + (quad << 5) + el;
    dstB[0]  = w0B;
    dstB[16] = w1B;
}

// ---------------------------------------------------------------------------
extern "C" void kernel_launch(void* const* d_in, const int* in_sizes, int n_in,
                              void* d_out, int out_size, void* d_ws, size_t ws_size,
                              hipStream_t stream)
{
    const float* scalar = (const float*)d_in[0];
    const float* ef     = (const float*)d_in[1];
    const int*   eidx   = (const int*)d_in[2];
    const float* C      = (const float*)d_in[3];
    const float* emb_w  = (const float*)d_in[4];
    const float* emb_b  = (const float*)d_in[5];
    const float* e_w    = (const float*)d_in[6];
    const float* conv_w = (const float*)d_in[7];
    const float* conv_b = (const float*)d_in[8];
    const float* out_w  = (const float*)d_in[9];
    const float* out_b  = (const float*)d_in[10];

    const int M = 40000;
    const size_t nodeElems = (size_t)M * H;            // 5,120,000

    float* s2s  = (float*)d_ws;
    float* sdst = s2s + nodeElems;
    float* conv = sdst + nodeElems;
    _Float16* wpk = (_Float16*)(conv + nodeElems);     // 167936 halves (10 mats + e_w)
    int* cnt    = (int*)(wpk + 167936);                // 40960 * CSTRIDE (padded)
    unsigned* bucket = (unsigned*)(cnt + 40960 * CSTRIDE); // 40960*CAP u32 (~7.9 MB)

    dim3 blk(256);

    pack_w<<<82, blk, 0, stream>>>(emb_w, conv_w, out_w, e_w, wpk, cnt);
    // s2s + scalar_dst + per-node edge buckets, interleaved blocks
    embscat_k<<<5000, blk, 0, stream>>>(scalar, wpk, emb_b, s2s, sdst,
                                        eidx, cnt, bucket);
    // conv = C * segment_sum(gather(sdst,col) * ef@e_w, row)   [2 nodes/wave]
    conv_k<<<5000, blk, 0, stream>>>(ef, sdst, wpk + 163840, C, cnt, bucket, conv);
    // fused tail
    out6_k<<<2500, blk, 0, stream>>>(conv, s2s, wpk + 4 * 16384,
                                     conv_b, out_b, (float*)d_out);
}

// Round 8
// 303.105 us; speedup vs baseline: 1.0535x; 1.0535x over previous
//
#include <hip/hip_runtime.h>
#include <hip/hip_bf16.h>

#define H 128
#define CAP 48
#define CSTRIDE 16   // one counter per 64B sector

typedef _Float16 f16x4 __attribute__((ext_vector_type(4)));
typedef _Float16 f16x8 __attribute__((ext_vector_type(8)));
typedef float    f32x4 __attribute__((ext_vector_type(4)));

__device__ __forceinline__ float silu_f(float v) {
    return v / (1.0f + __expf(-v));
}

// ---------------------------------------------------------------------------
// Weight pre-pack: 10 matrices [128k][128c] f32 -> fp16 A-frag layout,
// plus e_w [32k][128c] -> fp16 B-frag layout. Zeroes padded counters.
// ---------------------------------------------------------------------------
__global__ __launch_bounds__(256)
void pack_w(const float* __restrict__ emb_w, const float* __restrict__ conv_w,
            const float* __restrict__ out_w, const float* __restrict__ e_w,
            _Float16* __restrict__ wpk, int* __restrict__ cnt)
{
    const int gid = blockIdx.x * 256 + threadIdx.x;     // 20992 = 82*256

#pragma unroll
    for (int i = 0; i < 32; ++i) {
        const int idx = gid + i * 20992;
        if (idx < 40960 * CSTRIDE) cnt[idx] = 0;
    }

    _Float16* dst = wpk + (size_t)gid * 8;
    if (gid < 20480) {
        const int mat = gid >> 11;
        const int r   = gid & 2047;
        const int ct  = r >> 8;
        const int kb  = (r >> 6) & 3;
        const int lane = r & 63;
        const float* W = (mat < 4) ? emb_w + mat * 16384
                       : (mat < 8) ? conv_w + (mat - 4) * 16384
                                   : out_w + (mat - 8) * 16384;
        const int m  = ct * 16 + (lane & 15);
        const int k0 = kb * 32 + (lane >> 4) * 8;
#pragma unroll
        for (int j = 0; j < 8; ++j)
            dst[j] = (_Float16)W[(k0 + j) * H + m];
    } else {
        const int r    = gid - 20480;                   // 0..511
        const int ct   = r >> 6;
        const int lane = r & 63;
        const int m    = ct * 16 + (lane & 15);
        const int k0   = (lane >> 4) * 8;
#pragma unroll
        for (int j = 0; j < 8; ++j)
            dst[j] = (_Float16)e_w[(k0 + j) * H + m];
    }
}

// ---------------------------------------------------------------------------
// MFMA helpers. CT = 16-col tiles per wave, ct0 = wave's first tile.
// ---------------------------------------------------------------------------
template <int CT>
__device__ __forceinline__ void mfma_layerT(const _Float16* __restrict__ w,
                                            const f16x8 bf[4], int ct0, int lane,
                                            f32x4 acc[CT])
{
#pragma unroll
    for (int c = 0; c < CT; ++c) acc[c] = (f32x4){0.f, 0.f, 0.f, 0.f};
#pragma unroll
    for (int kb = 0; kb < 4; ++kb) {
#pragma unroll
        for (int ctl = 0; ctl < CT; ++ctl) {
            f16x8 af = *(const f16x8*)(w + ((size_t)((ct0 + ctl) * 4 + kb) * 64 + lane) * 8);
            acc[ctl] = __builtin_amdgcn_mfma_f32_16x16x32_f16(af, bf[kb], acc[ctl], 0, 0, 0);
        }
    }
}

template <int CT>
__device__ __forceinline__ void store_stripT(_Float16* strip, const f32x4 acc[CT],
                                             const float* bias, int ct0, int rl, int quad)
{
#pragma unroll
    for (int ctl = 0; ctl < CT; ++ctl) {
        const int c = (ct0 + ctl) * 16 + quad * 4;
        float4 bb = *(const float4*)(bias + c);
        f16x4 hv = {(_Float16)silu_f(acc[ctl][0] + bb.x),
                    (_Float16)silu_f(acc[ctl][1] + bb.y),
                    (_Float16)silu_f(acc[ctl][2] + bb.z),
                    (_Float16)silu_f(acc[ctl][3] + bb.w)};
        *(f16x4*)(strip + rl * 136 + c) = hv;
    }
}

template <int CT>
__device__ __forceinline__ void store_strip_rawT(_Float16* strip, const f32x4 t[CT],
                                                 int ct0, int rl, int quad)
{
#pragma unroll
    for (int ctl = 0; ctl < CT; ++ctl) {
        const int c = (ct0 + ctl) * 16 + quad * 4;
        f16x4 hv = {(_Float16)t[ctl][0], (_Float16)t[ctl][1],
                    (_Float16)t[ctl][2], (_Float16)t[ctl][3]};
        *(f16x4*)(strip + rl * 136 + c) = hv;
    }
}

__device__ __forceinline__ void load_bf(const _Float16* strip, f16x8 bf[4],
                                        int rl, int quad)
{
#pragma unroll
    for (int kb = 0; kb < 4; ++kb)
        bf[kb] = *(const f16x8*)(strip + rl * 136 + kb * 32 + quad * 8);
}

// ---------------------------------------------------------------------------
// embscat_k: 3750 blocks, interleaved 2:1.
//   blockIdx%3 in {0,1}: bucket scatter (one atomic pass) + ef L3-warming
//   blockIdx%3 == 2    : emb2, barrier-free — each WAVE owns a full 16-row
//                        strip (CT=8): LDS round-trip is same-wave, no syncs.
// ---------------------------------------------------------------------------
__global__ __launch_bounds__(256)
void embscat_k(const float* __restrict__ x, const _Float16* __restrict__ wpk,
               const float* __restrict__ emb_b,
               float* __restrict__ s2s, float* __restrict__ sdst,
               const int* __restrict__ eidx, int* __restrict__ cnt,
               unsigned* __restrict__ bucket, const float* __restrict__ ef)
{
    __shared__ _Float16 hs[4][16 * 136];
    const int g = blockIdx.x / 3, r = blockIdx.x % 3;

    if (r < 2) {
        // ---- bucket scatter ----
        const int e = (g * 2 + r) * 256 + threadIdx.x;  // 640000 exact
        const int2 rc = ((const int2*)eidx)[e];
        const int b = (unsigned)e / 160000u;
        const int key = b * 10000 + rc.x;
        const int pos = atomicAdd(&cnt[key * CSTRIDE], 1);
        if (pos < CAP)
            bucket[(size_t)key * CAP + pos] =
                ((unsigned)(e - b * 160000) << 14) | (unsigned)rc.y;
        // ---- ef L3 warm: touch both 64B sectors of this edge's 128B row ----
        const float w0 = ef[(size_t)e * 32];
        const float w1 = ef[(size_t)e * 32 + 16];
        asm volatile("" :: "v"(w0), "v"(w1));   // keep loads live (rule #17)
        return;
    }

    // ---- emb2: wave = (msel, rowgroup), full 128 cols, own strip ----
    const int tid  = threadIdx.x;
    const int lane = tid & 63;
    const int wid  = tid >> 6;
    const int msel = wid & 1;
    const int rg   = wid >> 1;
    const int rl   = lane & 15;
    const int quad = lane >> 4;
    const int row  = g * 32 + rg * 16 + rl;             // g in 0..1249
    const size_t rbase = (size_t)row * H;

    f16x8 bf[4];
#pragma unroll
    for (int kb = 0; kb < 4; ++kb) {
        const int kc = kb * 32 + quad * 8;
        float4 v0 = *(const float4*)(x + rbase + kc);
        float4 v1 = *(const float4*)(x + rbase + kc + 4);
        bf[kb] = (f16x8){(_Float16)v0.x, (_Float16)v0.y, (_Float16)v0.z, (_Float16)v0.w,
                         (_Float16)v1.x, (_Float16)v1.y, (_Float16)v1.z, (_Float16)v1.w};
    }

    const _Float16* wm = wpk + (size_t)msel * 2 * 16384;
    _Float16* strip = hs[wid];
    const float* bias0 = emb_b + msel * 2 * H;

    f32x4 acc[8];
    mfma_layerT<8>(wm, bf, 0, lane, acc);
    store_stripT<8>(strip, acc, bias0, 0, rl, quad);
    __builtin_amdgcn_sched_barrier(0);                  // pin ds_write < ds_read
    load_bf(strip, bf, rl, quad);                       // same wave: no barrier
    mfma_layerT<8>(wm + 16384, bf, 0, lane, acc);

    float* outp = msel ? sdst : s2s;
    const float* bias1 = bias0 + H;
#pragma unroll
    for (int ctl = 0; ctl < 8; ++ctl) {
        const int c = ctl * 16 + quad * 4;
        float4 bb = *(const float4*)(bias1 + c);
        float4 v;
        v.x = silu_f(acc[ctl][0] + bb.x);
        v.y = silu_f(acc[ctl][1] + bb.y);
        v.z = silu_f(acc[ctl][2] + bb.z);
        v.w = silu_f(acc[ctl][3] + bb.w);
        *(float4*)(outp + rbase + c) = v;
    }
}

// ---------------------------------------------------------------------------
// out6_k: barrier-free fused tail. Each wave owns a full 16-row strip
// (CT=8, 625 blocks x 4 waves x 16 rows): all LDS round-trips same-wave.
// ---------------------------------------------------------------------------
__global__ __launch_bounds__(256)
void out6_k(const float* __restrict__ conv, const float* __restrict__ s2s,
            const _Float16* __restrict__ w6,   // mats 4..9
            const float* __restrict__ conv_b, const float* __restrict__ out_b,
            float* __restrict__ y)
{
    __shared__ _Float16 hs[4][16 * 136];
    const int tid  = threadIdx.x;
    const int lane = tid & 63;
    const int wid  = tid >> 6;
    const int rl   = lane & 15;
    const int quad = lane >> 4;
    const int row  = blockIdx.x * 64 + wid * 16 + rl;   // 625 blocks
    const size_t rbase = (size_t)row * H;
    _Float16* strip = hs[wid];

    f16x8 bf[4];
#pragma unroll
    for (int kb = 0; kb < 4; ++kb) {
        const int kc = kb * 32 + quad * 8;
        float4 v0 = *(const float4*)(conv + rbase + kc);
        float4 v1 = *(const float4*)(conv + rbase + kc + 4);
        bf[kb] = (f16x8){(_Float16)v0.x, (_Float16)v0.y, (_Float16)v0.z, (_Float16)v0.w,
                         (_Float16)v1.x, (_Float16)v1.y, (_Float16)v1.z, (_Float16)v1.w};
    }

    f32x4 acc[8], tD[8];

    // L0: hidden of residual-1
    mfma_layerT<8>(w6, bf, 0, lane, acc);
    store_stripT<8>(strip, acc, conv_b, 0, rl, quad);
    __builtin_amdgcn_sched_barrier(0);
    load_bf(strip, bf, rl, quad);

    // L1: t = conv + mlp_out
    mfma_layerT<8>(w6 + 16384, bf, 0, lane, acc);
#pragma unroll
    for (int ctl = 0; ctl < 8; ++ctl) {
        const int c = ctl * 16 + quad * 4;
        float4 bb = *(const float4*)(conv_b + H + c);
        float4 cv = *(const float4*)(conv + rbase + c);
        tD[ctl][0] = cv.x + silu_f(acc[ctl][0] + bb.x);
        tD[ctl][1] = cv.y + silu_f(acc[ctl][1] + bb.y);
        tD[ctl][2] = cv.z + silu_f(acc[ctl][2] + bb.z);
        tD[ctl][3] = cv.w + silu_f(acc[ctl][3] + bb.w);
    }
    store_strip_rawT<8>(strip, tD, 0, rl, quad);
    __builtin_amdgcn_sched_barrier(0);
    load_bf(strip, bf, rl, quad);

    // L2: hidden of residual-2
    mfma_layerT<8>(w6 + 2 * 16384, bf, 0, lane, acc);
    store_stripT<8>(strip, acc, conv_b + 2 * H, 0, rl, quad);
    __builtin_amdgcn_sched_barrier(0);
    load_bf(strip, bf, rl, quad);

    // L3: t += mlp_out;  z = t * s2s
    mfma_layerT<8>(w6 + 3 * 16384, bf, 0, lane, acc);
#pragma unroll
    for (int ctl = 0; ctl < 8; ++ctl) {
        const int c = ctl * 16 + quad * 4;
        float4 bb = *(const float4*)(conv_b + 3 * H + c);
        float4 sv = *(const float4*)(s2s + rbase + c);
        tD[ctl][0] = (tD[ctl][0] + silu_f(acc[ctl][0] + bb.x)) * sv.x;
        tD[ctl][1] = (tD[ctl][1] + silu_f(acc[ctl][1] + bb.y)) * sv.y;
        tD[ctl][2] = (tD[ctl][2] + silu_f(acc[ctl][2] + bb.z)) * sv.z;
        tD[ctl][3] = (tD[ctl][3] + silu_f(acc[ctl][3] + bb.w)) * sv.w;
    }
    store_strip_rawT<8>(strip, tD, 0, rl, quad);
    __builtin_amdgcn_sched_barrier(0);
    load_bf(strip, bf, rl, quad);

    // L4: hidden of final residual
    mfma_layerT<8>(w6 + 4 * 16384, bf, 0, lane, acc);
    store_stripT<8>(strip, acc, out_b, 0, rl, quad);
    __builtin_amdgcn_sched_barrier(0);
    load_bf(strip, bf, rl, quad);

    // L5: out = z + mlp_out
    mfma_layerT<8>(w6 + 5 * 16384, bf, 0, lane, acc);
#pragma unroll
    for (int ctl = 0; ctl < 8; ++ctl) {
        const int c = ctl * 16 + quad * 4;
        float4 bb = *(const float4*)(out_b + H + c);
        float4 v;
        v.x = tD[ctl][0] + silu_f(acc[ctl][0] + bb.x);
        v.y = tD[ctl][1] + silu_f(acc[ctl][1] + bb.y);
        v.z = tD[ctl][2] + silu_f(acc[ctl][2] + bb.z);
        v.w = tD[ctl][3] + silu_f(acc[ctl][3] + bb.w);
        *(float4*)(y + rbase + c) = v;
    }
}

// ---------------------------------------------------------------------------
// Gather-reduce (R5 structure, proven): 1 wave per node, 16-edge tiles,
// inline-asm 34-load bursts, packed u32 bucket entries.
// ---------------------------------------------------------------------------
#define GLD(dst, p, offlit) \
    asm volatile("global_load_dword %0, %1, off offset:" offlit \
                 : "=v"(dst) : "v"(p))
#define GLDX4(dst, p, offlit) \
    asm volatile("global_load_dwordx4 %0, %1, off offset:" offlit \
                 : "=v"(dst) : "v"(p))

__global__ __launch_bounds__(256, 2)
void conv_k(const float* __restrict__ ef, const float* __restrict__ sdst,
            const _Float16* __restrict__ ewpk, const float* __restrict__ C,
            const int* __restrict__ cnt, const unsigned* __restrict__ bucket,
            float* __restrict__ conv)
{
    const int tid  = threadIdx.x;
    const int lane = tid & 63;
    const int el   = lane & 15;
    const int quad = lane >> 4;
    const int nid  = blockIdx.x * 4 + (tid >> 6);   // 10000 blocks x 4 waves
    const int b    = (unsigned)nid / 10000u;
    const int ebase = b * 160000;
    const int srow  = b * 10000;

    const int n = min(cnt[nid * CSTRIDE], CAP);
    const unsigned* bk = bucket + (size_t)nid * CAP;

    f16x8 bw[8];
#pragma unroll
    for (int ct = 0; ct < 8; ++ct)
        bw[ct] = *(const f16x8*)(ewpk + ((size_t)((ct << 6) + lane)) * 8);

    float part[8];
#pragma unroll
    for (int ct = 0; ct < 8; ++ct) part[ct] = 0.f;

#pragma unroll 1
    for (int base = 0; base < n; base += 16) {
        const int rem = n - base;
        const bool ok = (el < rem);
        const unsigned m = ok ? bk[base + el] : 0u;

        const int sc0 = srow + (__shfl((int)m, (quad << 2) | 0, 64) & 0x3FFF);
        const int sc1 = srow + (__shfl((int)m, (quad << 2) | 1, 64) & 0x3FFF);
        const int sc2 = srow + (__shfl((int)m, (quad << 2) | 2, 64) & 0x3FFF);
        const int sc3 = srow + (__shfl((int)m, (quad << 2) | 3, 64) & 0x3FFF);

        const float* pe = ef + (size_t)(ebase + (int)(m >> 14)) * 32 + (quad << 3);
        const float* p0 = sdst + (size_t)sc0 * H + el;
        const float* p1 = sdst + (size_t)sc1 * H + el;
        const float* p2 = sdst + (size_t)sc2 * H + el;
        const float* p3 = sdst + (size_t)sc3 * H + el;

        f32x4 v0, v1;
        GLDX4(v0, pe, "0");
        GLDX4(v1, pe, "16");
        float s0[8], s1[8], s2[8], s3[8];
        GLD(s0[0], p0, "0");   GLD(s0[1], p0, "64");  GLD(s0[2], p0, "128");
        GLD(s0[3], p0, "192"); GLD(s0[4], p0, "256"); GLD(s0[5], p0, "320");
        GLD(s0[6], p0, "384"); GLD(s0[7], p0, "448");
        GLD(s1[0], p1, "0");   GLD(s1[1], p1, "64");  GLD(s1[2], p1, "128");
        GLD(s1[3], p1, "192"); GLD(s1[4], p1, "256"); GLD(s1[5], p1, "320");
        GLD(s1[6], p1, "384"); GLD(s1[7], p1, "448");
        GLD(s2[0], p2, "0");   GLD(s2[1], p2, "64");  GLD(s2[2], p2, "128");
        GLD(s2[3], p2, "192"); GLD(s2[4], p2, "256"); GLD(s2[5], p2, "320");
        GLD(s2[6], p2, "384"); GLD(s2[7], p2, "448");
        GLD(s3[0], p3, "0");   GLD(s3[1], p3, "64");  GLD(s3[2], p3, "128");
        GLD(s3[3], p3, "192"); GLD(s3[4], p3, "256"); GLD(s3[5], p3, "320");
        GLD(s3[6], p3, "384"); GLD(s3[7], p3, "448");

        asm volatile("s_waitcnt vmcnt(0)" ::: "memory");
        __builtin_amdgcn_sched_barrier(0);

        const f16x8 af = {
            ok ? (_Float16)v0[0] : (_Float16)0.f, ok ? (_Float16)v0[1] : (_Float16)0.f,
            ok ? (_Float16)v0[2] : (_Float16)0.f, ok ? (_Float16)v0[3] : (_Float16)0.f,
            ok ? (_Float16)v1[0] : (_Float16)0.f, ok ? (_Float16)v1[1] : (_Float16)0.f,
            ok ? (_Float16)v1[2] : (_Float16)0.f, ok ? (_Float16)v1[3] : (_Float16)0.f};

#pragma unroll
        for (int ct = 0; ct < 8; ++ct) {
            f32x4 acc = __builtin_amdgcn_mfma_f32_16x16x32_f16(
                af, bw[ct], (f32x4){0.f, 0.f, 0.f, 0.f}, 0, 0, 0);
            part[ct] += acc[0] * s0[ct] + acc[1] * s1[ct]
                      + acc[2] * s2[ct] + acc[3] * s3[ct];
        }
    }

    const float Cb = C[b];
    float w0 = 0.f, w1 = 0.f;
#pragma unroll
    for (int ct = 0; ct < 8; ++ct) {
        float v = part[ct];
        v += __shfl_xor(v, 16, 64);
        v += __shfl_xor(v, 32, 64);
        v *= Cb;
        if ((ct >> 1) == quad) { if (ct & 1) w1 = v; else w0 = v; }
    }
    float* dst = conv + (size_t)nid * H + (quad << 5) + el;
    dst[0]  = w0;
    dst[16] = w1;
}

// ---------------------------------------------------------------------------
extern "C" void kernel_launch(void* const* d_in, const int* in_sizes, int n_in,
                              void* d_out, int out_size, void* d_ws, size_t ws_size,
                              hipStream_t stream)
{
    const float* scalar = (const float*)d_in[0];
    const float* ef     = (const float*)d_in[1];
    const int*   eidx   = (const int*)d_in[2];
    const float* C      = (const float*)d_in[3];
    const float* emb_w  = (const float*)d_in[4];
    const float* emb_b  = (const float*)d_in[5];
    const float* e_w    = (const float*)d_in[6];
    const float* conv_w = (const float*)d_in[7];
    const float* conv_b = (const float*)d_in[8];
    const float* out_w  = (const float*)d_in[9];
    const float* out_b  = (const float*)d_in[10];

    const int M = 40000;
    const size_t nodeElems = (size_t)M * H;            // 5,120,000

    float* s2s  = (float*)d_ws;
    float* sdst = s2s + nodeElems;
    float* conv = sdst + nodeElems;
    _Float16* wpk = (_Float16*)(conv + nodeElems);     // 167936 halves (10 mats + e_w)
    int* cnt    = (int*)(wpk + 167936);                // 40960 * CSTRIDE (padded)
    unsigned* bucket = (unsigned*)(cnt + 40960 * CSTRIDE); // 40960*CAP u32 (~7.9 MB)

    dim3 blk(256);

    pack_w<<<82, blk, 0, stream>>>(emb_w, conv_w, out_w, e_w, wpk, cnt);
    // s2s + scalar_dst + buckets + ef L3-warm, interleaved 2:1
    embscat_k<<<3750, blk, 0, stream>>>(scalar, wpk, emb_b, s2s, sdst,
                                        eidx, cnt, bucket, ef);
    // conv = C * segment_sum(gather(sdst,col) * ef@e_w, row)
    conv_k<<<10000, blk, 0, stream>>>(ef, sdst, wpk + 163840, C, cnt, bucket, conv);
    // fused tail (barrier-free)
    out6_k<<<625, blk, 0, stream>>>(conv, s2s, wpk + 4 * 16384,
                                    conv_b, out_b, (float*)d_out);
}

// Round 9
// 274.629 us; speedup vs baseline: 1.1628x; 1.1037x over previous
//
#include <hip/hip_runtime.h>
#include <hip/hip_bf16.h>

#define H 128
#define CAP 48
#define CSTRIDE 16   // one counter per 64B sector

typedef _Float16 f16x4 __attribute__((ext_vector_type(4)));
typedef _Float16 f16x8 __attribute__((ext_vector_type(8)));
typedef float    f32x4 __attribute__((ext_vector_type(4)));

__device__ __forceinline__ float silu_f(float v) {
    return v / (1.0f + __expf(-v));
}

// ---------------------------------------------------------------------------
// Weight pre-pack: 10 matrices [128k][128c] f32 -> fp16 A-frag layout,
// plus e_w [32k][128c] -> fp16 B-frag layout. Zeroes padded counters.
// ---------------------------------------------------------------------------
__global__ __launch_bounds__(256)
void pack_w(const float* __restrict__ emb_w, const float* __restrict__ conv_w,
            const float* __restrict__ out_w, const float* __restrict__ e_w,
            _Float16* __restrict__ wpk, int* __restrict__ cnt)
{
    const int gid = blockIdx.x * 256 + threadIdx.x;     // 20992 = 82*256

#pragma unroll
    for (int i = 0; i < 32; ++i) {
        const int idx = gid + i * 20992;
        if (idx < 40960 * CSTRIDE) cnt[idx] = 0;
    }

    _Float16* dst = wpk + (size_t)gid * 8;
    if (gid < 20480) {
        const int mat = gid >> 11;
        const int r   = gid & 2047;
        const int ct  = r >> 8;
        const int kb  = (r >> 6) & 3;
        const int lane = r & 63;
        const float* W = (mat < 4) ? emb_w + mat * 16384
                       : (mat < 8) ? conv_w + (mat - 4) * 16384
                                   : out_w + (mat - 8) * 16384;
        const int m  = ct * 16 + (lane & 15);
        const int k0 = kb * 32 + (lane >> 4) * 8;
#pragma unroll
        for (int j = 0; j < 8; ++j)
            dst[j] = (_Float16)W[(k0 + j) * H + m];
    } else {
        const int r    = gid - 20480;                   // 0..511
        const int ct   = r >> 6;
        const int lane = r & 63;
        const int m    = ct * 16 + (lane & 15);
        const int k0   = (lane >> 4) * 8;
#pragma unroll
        for (int j = 0; j < 8; ++j)
            dst[j] = (_Float16)e_w[(k0 + j) * H + m];
    }
}

// ---------------------------------------------------------------------------
// MFMA helpers. CT = 16-col tiles per wave, ct0 = wave's first tile.
// ---------------------------------------------------------------------------
template <int CT>
__device__ __forceinline__ void mfma_layerT(const _Float16* __restrict__ w,
                                            const f16x8 bf[4], int ct0, int lane,
                                            f32x4 acc[CT])
{
#pragma unroll
    for (int c = 0; c < CT; ++c) acc[c] = (f32x4){0.f, 0.f, 0.f, 0.f};
#pragma unroll
    for (int kb = 0; kb < 4; ++kb) {
#pragma unroll
        for (int ctl = 0; ctl < CT; ++ctl) {
            f16x8 af = *(const f16x8*)(w + ((size_t)((ct0 + ctl) * 4 + kb) * 64 + lane) * 8);
            acc[ctl] = __builtin_amdgcn_mfma_f32_16x16x32_f16(af, bf[kb], acc[ctl], 0, 0, 0);
        }
    }
}

template <int CT>
__device__ __forceinline__ void store_stripT(_Float16* strip, const f32x4 acc[CT],
                                             const float* bias, int ct0, int rl, int quad)
{
#pragma unroll
    for (int ctl = 0; ctl < CT; ++ctl) {
        const int c = (ct0 + ctl) * 16 + quad * 4;
        float4 bb = *(const float4*)(bias + c);
        f16x4 hv = {(_Float16)silu_f(acc[ctl][0] + bb.x),
                    (_Float16)silu_f(acc[ctl][1] + bb.y),
                    (_Float16)silu_f(acc[ctl][2] + bb.z),
                    (_Float16)silu_f(acc[ctl][3] + bb.w)};
        *(f16x4*)(strip + rl * 136 + c) = hv;
    }
}

template <int CT>
__device__ __forceinline__ void store_strip_rawT(_Float16* strip, const f32x4 t[CT],
                                                 int ct0, int rl, int quad)
{
#pragma unroll
    for (int ctl = 0; ctl < CT; ++ctl) {
        const int c = (ct0 + ctl) * 16 + quad * 4;
        f16x4 hv = {(_Float16)t[ctl][0], (_Float16)t[ctl][1],
                    (_Float16)t[ctl][2], (_Float16)t[ctl][3]};
        *(f16x4*)(strip + rl * 136 + c) = hv;
    }
}

__device__ __forceinline__ void load_bf(const _Float16* strip, f16x8 bf[4],
                                        int rl, int quad)
{
#pragma unroll
    for (int kb = 0; kb < 4; ++kb)
        bf[kb] = *(const f16x8*)(strip + rl * 136 + kb * 32 + quad * 8);
}

// ---------------------------------------------------------------------------
// embscat_k: 3750 blocks, interleaved 2:1 (unchanged from R8).
//   blockIdx%3 in {0,1}: bucket scatter (one atomic pass) + ef L3-warming
//   blockIdx%3 == 2    : emb2, barrier-free (wave owns full 16-row strip)
// ---------------------------------------------------------------------------
__global__ __launch_bounds__(256)
void embscat_k(const float* __restrict__ x, const _Float16* __restrict__ wpk,
               const float* __restrict__ emb_b,
               float* __restrict__ s2s, float* __restrict__ sdst,
               const int* __restrict__ eidx, int* __restrict__ cnt,
               unsigned* __restrict__ bucket, const float* __restrict__ ef)
{
    __shared__ _Float16 hs[4][16 * 136];
    const int g = blockIdx.x / 3, r = blockIdx.x % 3;

    if (r < 2) {
        // ---- bucket scatter ----
        const int e = (g * 2 + r) * 256 + threadIdx.x;  // 640000 exact
        const int2 rc = ((const int2*)eidx)[e];
        const int b = (unsigned)e / 160000u;
        const int key = b * 10000 + rc.x;
        const int pos = atomicAdd(&cnt[key * CSTRIDE], 1);
        if (pos < CAP)
            bucket[(size_t)key * CAP + pos] =
                ((unsigned)(e - b * 160000) << 14) | (unsigned)rc.y;
        // ---- ef L3 warm: touch both 64B sectors of this edge's 128B row ----
        const float w0 = ef[(size_t)e * 32];
        const float w1 = ef[(size_t)e * 32 + 16];
        asm volatile("" :: "v"(w0), "v"(w1));   // keep loads live (rule #17)
        return;
    }

    // ---- emb2: wave = (msel, rowgroup), full 128 cols, own strip ----
    const int tid  = threadIdx.x;
    const int lane = tid & 63;
    const int wid  = tid >> 6;
    const int msel = wid & 1;
    const int rg   = wid >> 1;
    const int rl   = lane & 15;
    const int quad = lane >> 4;
    const int row  = g * 32 + rg * 16 + rl;             // g in 0..1249
    const size_t rbase = (size_t)row * H;

    f16x8 bf[4];
#pragma unroll
    for (int kb = 0; kb < 4; ++kb) {
        const int kc = kb * 32 + quad * 8;
        float4 v0 = *(const float4*)(x + rbase + kc);
        float4 v1 = *(const float4*)(x + rbase + kc + 4);
        bf[kb] = (f16x8){(_Float16)v0.x, (_Float16)v0.y, (_Float16)v0.z, (_Float16)v0.w,
                         (_Float16)v1.x, (_Float16)v1.y, (_Float16)v1.z, (_Float16)v1.w};
    }

    const _Float16* wm = wpk + (size_t)msel * 2 * 16384;
    _Float16* strip = hs[wid];
    const float* bias0 = emb_b + msel * 2 * H;

    f32x4 acc[8];
    mfma_layerT<8>(wm, bf, 0, lane, acc);
    store_stripT<8>(strip, acc, bias0, 0, rl, quad);
    __builtin_amdgcn_sched_barrier(0);                  // pin ds_write < ds_read
    load_bf(strip, bf, rl, quad);                       // same wave: no barrier
    mfma_layerT<8>(wm + 16384, bf, 0, lane, acc);

    float* outp = msel ? sdst : s2s;
    const float* bias1 = bias0 + H;
#pragma unroll
    for (int ctl = 0; ctl < 8; ++ctl) {
        const int c = ctl * 16 + quad * 4;
        float4 bb = *(const float4*)(bias1 + c);
        float4 v;
        v.x = silu_f(acc[ctl][0] + bb.x);
        v.y = silu_f(acc[ctl][1] + bb.y);
        v.z = silu_f(acc[ctl][2] + bb.z);
        v.w = silu_f(acc[ctl][3] + bb.w);
        *(float4*)(outp + rbase + c) = v;
    }
}

// ---------------------------------------------------------------------------
// convout_k: FUSED conv + out6. 2500 blocks x 4 waves; block owns rows
// 16b..16b+15 end-to-end.
// Phase 1 (per wave, 4 nodes): R5 gather-burst loop -> cross-quad reduce ->
//   C scale -> deposit row into LDS (f16 strip for MFMA input + f32 copy for
//   the exact residual). Numerics identical to the standalone path.
// __syncthreads.
// Phase 2: R0-proven column-split out6 (ct0 = wid*2, CT=2), bf/cv from LDS,
//   y written directly. Saves the conv array round-trip + one launch.
// ---------------------------------------------------------------------------
#define GLD(dst, p, offlit) \
    asm volatile("global_load_dword %0, %1, off offset:" offlit \
                 : "=v"(dst) : "v"(p))
#define GLDX4(dst, p, offlit) \
    asm volatile("global_load_dwordx4 %0, %1, off offset:" offlit \
                 : "=v"(dst) : "v"(p))

__global__ __launch_bounds__(256, 3)
void convout_k(const float* __restrict__ ef, const float* __restrict__ sdst,
               const _Float16* __restrict__ ewpk, const float* __restrict__ C,
               const int* __restrict__ cnt, const unsigned* __restrict__ bucket,
               const float* __restrict__ s2s, const _Float16* __restrict__ w6,
               const float* __restrict__ conv_b, const float* __restrict__ out_b,
               float* __restrict__ y)
{
    __shared__ _Float16 hsC[16 * 136];      // conv rows, f16 (MFMA input)
    __shared__ float    cvf[16 * 128];      // conv rows, f32 (exact residual)
    __shared__ _Float16 hs0[16 * 136], hs1[16 * 136];

    const int tid  = threadIdx.x;
    const int lane = tid & 63;
    const int el   = lane & 15;
    const int quad = lane >> 4;
    const int wid  = tid >> 6;
    const int nbase = blockIdx.x * 16;              // 2500 blocks
    const int b     = nbase / 10000;                // 625 blocks per batch
    const int ebase = b * 160000;
    const int srow  = b * 10000;
    const float Cb  = C[b];

    // e_w B-frags: 8 col-tiles x f16x8 (32 VGPRs)
    f16x8 bw[8];
#pragma unroll
    for (int ct = 0; ct < 8; ++ct)
        bw[ct] = *(const f16x8*)(ewpk + ((size_t)((ct << 6) + lane)) * 8);

    // ---------------- phase 1: gather-reduce 4 nodes per wave ----------------
#pragma unroll 1
    for (int j = 0; j < 4; ++j) {
        const int nid = nbase + wid * 4 + j;
        const int n = min(cnt[nid * CSTRIDE], CAP);
        const unsigned* bk = bucket + (size_t)nid * CAP;

        float part[8];
#pragma unroll
        for (int ct = 0; ct < 8; ++ct) part[ct] = 0.f;

#pragma unroll 1
        for (int base = 0; base < n; base += 16) {
            const int rem = n - base;
            const bool ok = (el < rem);
            const unsigned m = ok ? bk[base + el] : 0u;

            const int sc0 = srow + (__shfl((int)m, (quad << 2) | 0, 64) & 0x3FFF);
            const int sc1 = srow + (__shfl((int)m, (quad << 2) | 1, 64) & 0x3FFF);
            const int sc2 = srow + (__shfl((int)m, (quad << 2) | 2, 64) & 0x3FFF);
            const int sc3 = srow + (__shfl((int)m, (quad << 2) | 3, 64) & 0x3FFF);

            const float* pe = ef + (size_t)(ebase + (int)(m >> 14)) * 32 + (quad << 3);
            const float* p0 = sdst + (size_t)sc0 * H + el;
            const float* p1 = sdst + (size_t)sc1 * H + el;
            const float* p2 = sdst + (size_t)sc2 * H + el;
            const float* p3 = sdst + (size_t)sc3 * H + el;

            f32x4 v0, v1;
            GLDX4(v0, pe, "0");
            GLDX4(v1, pe, "16");
            float s0[8], s1[8], s2[8], s3[8];
            GLD(s0[0], p0, "0");   GLD(s0[1], p0, "64");  GLD(s0[2], p0, "128");
            GLD(s0[3], p0, "192"); GLD(s0[4], p0, "256"); GLD(s0[5], p0, "320");
            GLD(s0[6], p0, "384"); GLD(s0[7], p0, "448");
            GLD(s1[0], p1, "0");   GLD(s1[1], p1, "64");  GLD(s1[2], p1, "128");
            GLD(s1[3], p1, "192"); GLD(s1[4], p1, "256"); GLD(s1[5], p1, "320");
            GLD(s1[6], p1, "384"); GLD(s1[7], p1, "448");
            GLD(s2[0], p2, "0");   GLD(s2[1], p2, "64");  GLD(s2[2], p2, "128");
            GLD(s2[3], p2, "192"); GLD(s2[4], p2, "256"); GLD(s2[5], p2, "320");
            GLD(s2[6], p2, "384"); GLD(s2[7], p2, "448");
            GLD(s3[0], p3, "0");   GLD(s3[1], p3, "64");  GLD(s3[2], p3, "128");
            GLD(s3[3], p3, "192"); GLD(s3[4], p3, "256"); GLD(s3[5], p3, "320");
            GLD(s3[6], p3, "384"); GLD(s3[7], p3, "448");

            asm volatile("s_waitcnt vmcnt(0)" ::: "memory");
            __builtin_amdgcn_sched_barrier(0);

            const f16x8 af = {
                ok ? (_Float16)v0[0] : (_Float16)0.f, ok ? (_Float16)v0[1] : (_Float16)0.f,
                ok ? (_Float16)v0[2] : (_Float16)0.f, ok ? (_Float16)v0[3] : (_Float16)0.f,
                ok ? (_Float16)v1[0] : (_Float16)0.f, ok ? (_Float16)v1[1] : (_Float16)0.f,
                ok ? (_Float16)v1[2] : (_Float16)0.f, ok ? (_Float16)v1[3] : (_Float16)0.f};

#pragma unroll
            for (int ct = 0; ct < 8; ++ct) {
                f32x4 acc = __builtin_amdgcn_mfma_f32_16x16x32_f16(
                    af, bw[ct], (f32x4){0.f, 0.f, 0.f, 0.f}, 0, 0, 0);
                part[ct] += acc[0] * s0[ct] + acc[1] * s1[ct]
                          + acc[2] * s2[ct] + acc[3] * s3[ct];
            }
        }

        // cross-quad reduce, scale by C, deposit row into LDS
        const int lr = wid * 4 + j;
        float w0 = 0.f, w1 = 0.f;
#pragma unroll
        for (int ct = 0; ct < 8; ++ct) {
            float v = part[ct];
            v += __shfl_xor(v, 16, 64);
            v += __shfl_xor(v, 32, 64);
            v *= Cb;
            if ((ct >> 1) == quad) { if (ct & 1) w1 = v; else w0 = v; }
        }
        const int c0 = (quad << 5) + el;
        cvf[lr * 128 + c0]      = w0;
        cvf[lr * 128 + c0 + 16] = w1;
        hsC[lr * 136 + c0]      = (_Float16)w0;
        hsC[lr * 136 + c0 + 16] = (_Float16)w1;
    }
    __syncthreads();

    // ---------------- phase 2: out6 tail on the block's 16 rows ----------------
    const int ct0 = wid * 2;
    const int rl  = el;
    const int row = nbase + rl;
    const size_t rbase = (size_t)row * H;

    f16x8 bf[4];
    load_bf(hsC, bf, rl, quad);

    f32x4 acc[2], tD[2];

    // L0: hidden of residual-1
    mfma_layerT<2>(w6, bf, ct0, lane, acc);
    store_stripT<2>(hs0, acc, conv_b, ct0, rl, quad);
    __syncthreads();
    load_bf(hs0, bf, rl, quad);

    // L1: t = conv + mlp_out
    mfma_layerT<2>(w6 + 16384, bf, ct0, lane, acc);
#pragma unroll
    for (int ctl = 0; ctl < 2; ++ctl) {
        const int c = (ct0 + ctl) * 16 + quad * 4;
        float4 bb = *(const float4*)(conv_b + H + c);
        float4 cv = *(const float4*)(cvf + rl * 128 + c);
        tD[ctl][0] = cv.x + silu_f(acc[ctl][0] + bb.x);
        tD[ctl][1] = cv.y + silu_f(acc[ctl][1] + bb.y);
        tD[ctl][2] = cv.z + silu_f(acc[ctl][2] + bb.z);
        tD[ctl][3] = cv.w + silu_f(acc[ctl][3] + bb.w);
    }
    store_strip_rawT<2>(hs1, tD, ct0, rl, quad);
    __syncthreads();
    load_bf(hs1, bf, rl, quad);

    // L2: hidden of residual-2
    mfma_layerT<2>(w6 + 2 * 16384, bf, ct0, lane, acc);
    store_stripT<2>(hs0, acc, conv_b + 2 * H, ct0, rl, quad);
    __syncthreads();
    load_bf(hs0, bf, rl, quad);

    // L3: t += mlp_out;  z = t * s2s
    mfma_layerT<2>(w6 + 3 * 16384, bf, ct0, lane, acc);
#pragma unroll
    for (int ctl = 0; ctl < 2; ++ctl) {
        const int c = (ct0 + ctl) * 16 + quad * 4;
        float4 bb = *(const float4*)(conv_b + 3 * H + c);
        float4 sv = *(const float4*)(s2s + rbase + c);
        tD[ctl][0] = (tD[ctl][0] + silu_f(acc[ctl][0] + bb.x)) * sv.x;
        tD[ctl][1] = (tD[ctl][1] + silu_f(acc[ctl][1] + bb.y)) * sv.y;
        tD[ctl][2] = (tD[ctl][2] + silu_f(acc[ctl][2] + bb.z)) * sv.z;
        tD[ctl][3] = (tD[ctl][3] + silu_f(acc[ctl][3] + bb.w)) * sv.w;
    }
    store_strip_rawT<2>(hs1, tD, ct0, rl, quad);
    __syncthreads();
    load_bf(hs1, bf, rl, quad);

    // L4: hidden of final residual
    mfma_layerT<2>(w6 + 4 * 16384, bf, ct0, lane, acc);
    store_stripT<2>(hs0, acc, out_b, ct0, rl, quad);
    __syncthreads();
    load_bf(hs0, bf, rl, quad);

    // L5: out = z + mlp_out
    mfma_layerT<2>(w6 + 5 * 16384, bf, ct0, lane, acc);
#pragma unroll
    for (int ctl = 0; ctl < 2; ++ctl) {
        const int c = (ct0 + ctl) * 16 + quad * 4;
        float4 bb = *(const float4*)(out_b + H + c);
        float4 v;
        v.x = tD[ctl][0] + silu_f(acc[ctl][0] + bb.x);
        v.y = tD[ctl][1] + silu_f(acc[ctl][1] + bb.y);
        v.z = tD[ctl][2] + silu_f(acc[ctl][2] + bb.z);
        v.w = tD[ctl][3] + silu_f(acc[ctl][3] + bb.w);
        *(float4*)(y + rbase + c) = v;
    }
}

// ---------------------------------------------------------------------------
extern "C" void kernel_launch(void* const* d_in, const int* in_sizes, int n_in,
                              void* d_out, int out_size, void* d_ws, size_t ws_size,
                              hipStream_t stream)
{
    const float* scalar = (const float*)d_in[0];
    const float* ef     = (const float*)d_in[1];
    const int*   eidx   = (const int*)d_in[2];
    const float* C      = (const float*)d_in[3];
    const float* emb_w  = (const float*)d_in[4];
    const float* emb_b  = (const float*)d_in[5];
    const float* e_w    = (const float*)d_in[6];
    const float* conv_w = (const float*)d_in[7];
    const float* conv_b = (const float*)d_in[8];
    const float* out_w  = (const float*)d_in[9];
    const float* out_b  = (const float*)d_in[10];

    const int M = 40000;
    const size_t nodeElems = (size_t)M * H;            // 5,120,000

    float* s2s  = (float*)d_ws;
    float* sdst = s2s + nodeElems;
    _Float16* wpk = (_Float16*)(sdst + nodeElems);     // 167936 halves (10 mats + e_w)
    int* cnt    = (int*)(wpk + 167936);                // 40960 * CSTRIDE (padded)
    unsigned* bucket = (unsigned*)(cnt + 40960 * CSTRIDE); // 40960*CAP u32 (~7.9 MB)

    dim3 blk(256);

    pack_w<<<82, blk, 0, stream>>>(emb_w, conv_w, out_w, e_w, wpk, cnt);
    // s2s + scalar_dst + buckets + ef L3-warm, interleaved 2:1
    embscat_k<<<3750, blk, 0, stream>>>(scalar, wpk, emb_b, s2s, sdst,
                                        eidx, cnt, bucket, ef);
    // fused: conv (gather-MFMA) + full out6 tail, conv array never leaves LDS
    convout_k<<<2500, blk, 0, stream>>>(ef, sdst, wpk + 163840, C, cnt, bucket,
                                        s2s, wpk + 4 * 16384,
                                        conv_b, out_b, (float*)d_out);
}

// Round 11
// 271.258 us; speedup vs baseline: 1.1772x; 1.0124x over previous
//
#include <hip/hip_runtime.h>
#include <hip/hip_bf16.h>

#define H 128
#define CAP 48
#define CSTRIDE 16   // one counter per 64B sector

typedef _Float16 f16x4 __attribute__((ext_vector_type(4)));
typedef _Float16 f16x8 __attribute__((ext_vector_type(8)));
typedef float    f32x4 __attribute__((ext_vector_type(4)));

__device__ __forceinline__ float silu_f(float v) {
    return v / (1.0f + __expf(-v));
}

// ---------------------------------------------------------------------------
// Weight pre-pack: 10 matrices [128k][128c] f32 -> fp16 A-frag layout,
// plus e_w [32k][128c] -> fp16 B-frag layout. Zeroes padded counters.
// ---------------------------------------------------------------------------
__global__ __launch_bounds__(256)
void pack_w(const float* __restrict__ emb_w, const float* __restrict__ conv_w,
            const float* __restrict__ out_w, const float* __restrict__ e_w,
            _Float16* __restrict__ wpk, int* __restrict__ cnt)
{
    const int gid = blockIdx.x * 256 + threadIdx.x;     // 20992 = 82*256

#pragma unroll
    for (int i = 0; i < 32; ++i) {
        const int idx = gid + i * 20992;
        if (idx < 40960 * CSTRIDE) cnt[idx] = 0;
    }

    _Float16* dst = wpk + (size_t)gid * 8;
    if (gid < 20480) {
        const int mat = gid >> 11;
        const int r   = gid & 2047;
        const int ct  = r >> 8;
        const int kb  = (r >> 6) & 3;
        const int lane = r & 63;
        const float* W = (mat < 4) ? emb_w + mat * 16384
                       : (mat < 8) ? conv_w + (mat - 4) * 16384
                                   : out_w + (mat - 8) * 16384;
        const int m  = ct * 16 + (lane & 15);
        const int k0 = kb * 32 + (lane >> 4) * 8;
#pragma unroll
        for (int j = 0; j < 8; ++j)
            dst[j] = (_Float16)W[(k0 + j) * H + m];
    } else {
        const int r    = gid - 20480;                   // 0..511
        const int ct   = r >> 6;
        const int lane = r & 63;
        const int m    = ct * 16 + (lane & 15);
        const int k0   = (lane >> 4) * 8;
#pragma unroll
        for (int j = 0; j < 8; ++j)
            dst[j] = (_Float16)e_w[(k0 + j) * H + m];
    }
}

// ---------------------------------------------------------------------------
// MFMA helpers. CT = 16-col tiles per wave, ct0 = wave's first tile.
// ---------------------------------------------------------------------------
template <int CT>
__device__ __forceinline__ void mfma_layerT(const _Float16* __restrict__ w,
                                            const f16x8 bf[4], int ct0, int lane,
                                            f32x4 acc[CT])
{
#pragma unroll
    for (int c = 0; c < CT; ++c) acc[c] = (f32x4){0.f, 0.f, 0.f, 0.f};
#pragma unroll
    for (int kb = 0; kb < 4; ++kb) {
#pragma unroll
        for (int ctl = 0; ctl < CT; ++ctl) {
            f16x8 af = *(const f16x8*)(w + ((size_t)((ct0 + ctl) * 4 + kb) * 64 + lane) * 8);
            acc[ctl] = __builtin_amdgcn_mfma_f32_16x16x32_f16(af, bf[kb], acc[ctl], 0, 0, 0);
        }
    }
}

template <int CT>
__device__ __forceinline__ void store_stripT(_Float16* strip, const f32x4 acc[CT],
                                             const float* bias, int ct0, int rl, int quad)
{
#pragma unroll
    for (int ctl = 0; ctl < CT; ++ctl) {
        const int c = (ct0 + ctl) * 16 + quad * 4;
        float4 bb = *(const float4*)(bias + c);
        f16x4 hv = {(_Float16)silu_f(acc[ctl][0] + bb.x),
                    (_Float16)silu_f(acc[ctl][1] + bb.y),
                    (_Float16)silu_f(acc[ctl][2] + bb.z),
                    (_Float16)silu_f(acc[ctl][3] + bb.w)};
        *(f16x4*)(strip + rl * 136 + c) = hv;
    }
}

template <int CT>
__device__ __forceinline__ void store_strip_rawT(_Float16* strip, const f32x4 t[CT],
                                                 int ct0, int rl, int quad)
{
#pragma unroll
    for (int ctl = 0; ctl < CT; ++ctl) {
        const int c = (ct0 + ctl) * 16 + quad * 4;
        f16x4 hv = {(_Float16)t[ctl][0], (_Float16)t[ctl][1],
                    (_Float16)t[ctl][2], (_Float16)t[ctl][3]};
        *(f16x4*)(strip + rl * 136 + c) = hv;
    }
}

__device__ __forceinline__ void load_bf(const _Float16* strip, f16x8 bf[4],
                                        int rl, int quad)
{
#pragma unroll
    for (int kb = 0; kb < 4; ++kb)
        bf[kb] = *(const f16x8*)(strip + rl * 136 + kb * 32 + quad * 8);
}

// ---------------------------------------------------------------------------
// embscat_k: 3750 blocks, interleaved 2:1 (R8/R9-proven).
//   blockIdx%3 in {0,1}: bucket scatter (one atomic pass) + ef L3-warming
//   blockIdx%3 == 2    : emb2, barrier-free (wave owns full 16-row strip)
// ---------------------------------------------------------------------------
__global__ __launch_bounds__(256)
void embscat_k(const float* __restrict__ x, const _Float16* __restrict__ wpk,
               const float* __restrict__ emb_b,
               float* __restrict__ s2s, float* __restrict__ sdst,
               const int* __restrict__ eidx, int* __restrict__ cnt,
               unsigned* __restrict__ bucket, const float* __restrict__ ef)
{
    __shared__ _Float16 hs[4][16 * 136];
    const int g = blockIdx.x / 3, r = blockIdx.x % 3;

    if (r < 2) {
        // ---- bucket scatter ----
        const int e = (g * 2 + r) * 256 + threadIdx.x;  // 640000 exact
        const int2 rc = ((const int2*)eidx)[e];
        const int b = (unsigned)e / 160000u;
        const int key = b * 10000 + rc.x;
        const int pos = atomicAdd(&cnt[key * CSTRIDE], 1);
        if (pos < CAP)
            bucket[(size_t)key * CAP + pos] =
                ((unsigned)(e - b * 160000) << 14) | (unsigned)rc.y;
        // ---- ef L3 warm: touch both 64B sectors of this edge's 128B row ----
        const float w0 = ef[(size_t)e * 32];
        const float w1 = ef[(size_t)e * 32 + 16];
        asm volatile("" :: "v"(w0), "v"(w1));   // keep loads live (rule #17)
        return;
    }

    // ---- emb2: wave = (msel, rowgroup), full 128 cols, own strip ----
    const int tid  = threadIdx.x;
    const int lane = tid & 63;
    const int wid  = tid >> 6;
    const int msel = wid & 1;
    const int rg   = wid >> 1;
    const int rl   = lane & 15;
    const int quad = lane >> 4;
    const int row  = g * 32 + rg * 16 + rl;             // g in 0..1249
    const size_t rbase = (size_t)row * H;

    f16x8 bf[4];
#pragma unroll
    for (int kb = 0; kb < 4; ++kb) {
        const int kc = kb * 32 + quad * 8;
        float4 v0 = *(const float4*)(x + rbase + kc);
        float4 v1 = *(const float4*)(x + rbase + kc + 4);
        bf[kb] = (f16x8){(_Float16)v0.x, (_Float16)v0.y, (_Float16)v0.z, (_Float16)v0.w,
                         (_Float16)v1.x, (_Float16)v1.y, (_Float16)v1.z, (_Float16)v1.w};
    }

    const _Float16* wm = wpk + (size_t)msel * 2 * 16384;
    _Float16* strip = hs[wid];
    const float* bias0 = emb_b + msel * 2 * H;

    f32x4 acc[8];
    mfma_layerT<8>(wm, bf, 0, lane, acc);
    store_stripT<8>(strip, acc, bias0, 0, rl, quad);
    __builtin_amdgcn_sched_barrier(0);                  // pin ds_write < ds_read
    load_bf(strip, bf, rl, quad);                       // same wave: no barrier
    mfma_layerT<8>(wm + 16384, bf, 0, lane, acc);

    float* outp = msel ? sdst : s2s;
    const float* bias1 = bias0 + H;
#pragma unroll
    for (int ctl = 0; ctl < 8; ++ctl) {
        const int c = ctl * 16 + quad * 4;
        float4 bb = *(const float4*)(bias1 + c);
        float4 v;
        v.x = silu_f(acc[ctl][0] + bb.x);
        v.y = silu_f(acc[ctl][1] + bb.y);
        v.z = silu_f(acc[ctl][2] + bb.z);
        v.w = silu_f(acc[ctl][3] + bb.w);
        *(float4*)(outp + rbase + c) = v;
    }
}

// ---------------------------------------------------------------------------
// convout_k: FUSED conv + out6 (R9 structure) + hoisted node descriptors:
// counts + tile0/tile1 bucket entries for all 4 nodes of the wave load in ONE
// parallel round (entries live in quad j's lanes, redistributed by shfl).
// All shfls execute UNCONDITIONALLY (full exec mask); masks applied after.
// ef stays f32 (R9-proven; no extra workspace).
// ---------------------------------------------------------------------------
#define GLD(dst, p, offlit) \
    asm volatile("global_load_dword %0, %1, off offset:" offlit \
                 : "=v"(dst) : "v"(p))
#define GLDX4(dst, p, offlit) \
    asm volatile("global_load_dwordx4 %0, %1, off offset:" offlit \
                 : "=v"(dst) : "v"(p))

__device__ __forceinline__ void gather_tile(
    const float* __restrict__ ef, const float* __restrict__ sdst,
    const f16x8 bw[8], unsigned m_ef, unsigned m0, unsigned m1,
    unsigned m2, unsigned m3, bool ok, int ebase, int srow,
    int el, int quad, float part[8])
{
    const int sc0 = srow + (int)(m0 & 0x3FFFu);
    const int sc1 = srow + (int)(m1 & 0x3FFFu);
    const int sc2 = srow + (int)(m2 & 0x3FFFu);
    const int sc3 = srow + (int)(m3 & 0x3FFFu);
    const float* pe = ef + ((size_t)(ebase + (int)(m_ef >> 14)) << 5) + (quad << 3);
    const float* p0 = sdst + (size_t)sc0 * H + el;
    const float* p1 = sdst + (size_t)sc1 * H + el;
    const float* p2 = sdst + (size_t)sc2 * H + el;
    const float* p3 = sdst + (size_t)sc3 * H + el;

    f32x4 v0, v1;
    GLDX4(v0, pe, "0");
    GLDX4(v1, pe, "16");
    float s0[8], s1[8], s2[8], s3[8];
    GLD(s0[0], p0, "0");   GLD(s0[1], p0, "64");  GLD(s0[2], p0, "128");
    GLD(s0[3], p0, "192"); GLD(s0[4], p0, "256"); GLD(s0[5], p0, "320");
    GLD(s0[6], p0, "384"); GLD(s0[7], p0, "448");
    GLD(s1[0], p1, "0");   GLD(s1[1], p1, "64");  GLD(s1[2], p1, "128");
    GLD(s1[3], p1, "192"); GLD(s1[4], p1, "256"); GLD(s1[5], p1, "320");
    GLD(s1[6], p1, "384"); GLD(s1[7], p1, "448");
    GLD(s2[0], p2, "0");   GLD(s2[1], p2, "64");  GLD(s2[2], p2, "128");
    GLD(s2[3], p2, "192"); GLD(s2[4], p2, "256"); GLD(s2[5], p2, "320");
    GLD(s2[6], p2, "384"); GLD(s2[7], p2, "448");
    GLD(s3[0], p3, "0");   GLD(s3[1], p3, "64");  GLD(s3[2], p3, "128");
    GLD(s3[3], p3, "192"); GLD(s3[4], p3, "256"); GLD(s3[5], p3, "320");
    GLD(s3[6], p3, "384"); GLD(s3[7], p3, "448");

    asm volatile("s_waitcnt vmcnt(0)" ::: "memory");
    __builtin_amdgcn_sched_barrier(0);

    const f16x8 af = {
        ok ? (_Float16)v0[0] : (_Float16)0.f, ok ? (_Float16)v0[1] : (_Float16)0.f,
        ok ? (_Float16)v0[2] : (_Float16)0.f, ok ? (_Float16)v0[3] : (_Float16)0.f,
        ok ? (_Float16)v1[0] : (_Float16)0.f, ok ? (_Float16)v1[1] : (_Float16)0.f,
        ok ? (_Float16)v1[2] : (_Float16)0.f, ok ? (_Float16)v1[3] : (_Float16)0.f};

#pragma unroll
    for (int ct = 0; ct < 8; ++ct) {
        f32x4 acc = __builtin_amdgcn_mfma_f32_16x16x32_f16(
            af, bw[ct], (f32x4){0.f, 0.f, 0.f, 0.f}, 0, 0, 0);
        part[ct] += acc[0] * s0[ct] + acc[1] * s1[ct]
                  + acc[2] * s2[ct] + acc[3] * s3[ct];
    }
}

__global__ __launch_bounds__(256, 3)
void convout_k(const float* __restrict__ ef, const float* __restrict__ sdst,
               const _Float16* __restrict__ ewpk, const float* __restrict__ C,
               const int* __restrict__ cnt, const unsigned* __restrict__ bucket,
               const float* __restrict__ s2s, const _Float16* __restrict__ w6,
               const float* __restrict__ conv_b, const float* __restrict__ out_b,
               float* __restrict__ y)
{
    __shared__ _Float16 hsC[16 * 136];      // conv rows, f16 (MFMA input)
    __shared__ float    cvf[16 * 128];      // conv rows, f32 (exact residual)
    __shared__ _Float16 hs0[16 * 136], hs1[16 * 136];

    const int tid  = threadIdx.x;
    const int lane = tid & 63;
    const int el   = lane & 15;
    const int quad = lane >> 4;
    const int wid  = tid >> 6;
    const int nbase = blockIdx.x * 16;              // 2500 blocks
    const int b     = nbase / 10000;                // 625 blocks per batch
    const int ebase = b * 160000;
    const int srow  = b * 10000;
    const float Cb  = C[b];
    const int n0    = nbase + (wid << 2);           // wave's first node

    // hoisted descriptors: 4 counts + tile0/tile1 entries, ONE parallel round
    int cn[4];
    cn[0] = cnt[(n0 + 0) * CSTRIDE];
    cn[1] = cnt[(n0 + 1) * CSTRIDE];
    cn[2] = cnt[(n0 + 2) * CSTRIDE];
    cn[3] = cnt[(n0 + 3) * CSTRIDE];
    const unsigned ent0 = bucket[(size_t)(n0 + quad) * CAP + el];        // node 'quad', slots 0..15
    const unsigned ent1 = bucket[(size_t)(n0 + quad) * CAP + 16 + el];   // node 'quad', slots 16..31

    // e_w B-frags: 8 col-tiles x f16x8 (32 VGPRs)
    f16x8 bw[8];
#pragma unroll
    for (int ct = 0; ct < 8; ++ct)
        bw[ct] = *(const f16x8*)(ewpk + ((size_t)((ct << 6) + lane)) * 8);

    // ---------------- phase 1: gather-reduce 4 nodes per wave ----------------
#pragma unroll
    for (int j = 0; j < 4; ++j) {
        const int nn = min(cn[j], CAP);
        const unsigned* bk = bucket + (size_t)(n0 + j) * CAP;
        const int sb = quad << 2;

        float part[8];
#pragma unroll
        for (int ct = 0; ct < 8; ++ct) part[ct] = 0.f;

        {   // tile 0 from preloaded ent0 (node j's entries live in quad j)
            const int rem = nn;
            const bool ok = el < rem;
            // shfls executed unconditionally by ALL lanes; mask applied after
            const unsigned eV = (unsigned)__shfl((int)ent0, (j << 4) | el, 64);
            const unsigned r0 = (unsigned)__shfl((int)ent0, (j << 4) | (sb + 0), 64);
            const unsigned r1 = (unsigned)__shfl((int)ent0, (j << 4) | (sb + 1), 64);
            const unsigned r2 = (unsigned)__shfl((int)ent0, (j << 4) | (sb + 2), 64);
            const unsigned r3 = (unsigned)__shfl((int)ent0, (j << 4) | (sb + 3), 64);
            const unsigned mef = ok ? eV : 0u;
            const unsigned q0 = (sb + 0 < rem) ? r0 : 0u;
            const unsigned q1 = (sb + 1 < rem) ? r1 : 0u;
            const unsigned q2 = (sb + 2 < rem) ? r2 : 0u;
            const unsigned q3 = (sb + 3 < rem) ? r3 : 0u;
            gather_tile(ef, sdst, bw, mef, q0, q1, q2, q3, ok, ebase, srow, el, quad, part);
        }
        if (nn > 16) {  // tile 1 from preloaded ent1
            const int rem = nn - 16;
            const bool ok = el < rem;
            const unsigned eV = (unsigned)__shfl((int)ent1, (j << 4) | el, 64);
            const unsigned r0 = (unsigned)__shfl((int)ent1, (j << 4) | (sb + 0), 64);
            const unsigned r1 = (unsigned)__shfl((int)ent1, (j << 4) | (sb + 1), 64);
            const unsigned r2 = (unsigned)__shfl((int)ent1, (j << 4) | (sb + 2), 64);
            const unsigned r3 = (unsigned)__shfl((int)ent1, (j << 4) | (sb + 3), 64);
            const unsigned mef = ok ? eV : 0u;
            const unsigned q0 = (sb + 0 < rem) ? r0 : 0u;
            const unsigned q1 = (sb + 1 < rem) ? r1 : 0u;
            const unsigned q2 = (sb + 2 < rem) ? r2 : 0u;
            const unsigned q3 = (sb + 3 < rem) ? r3 : 0u;
            gather_tile(ef, sdst, bw, mef, q0, q1, q2, q3, ok, ebase, srow, el, quad, part);
        }
#pragma unroll 1
        for (int base = 32; base < nn; base += 16) {  // rare tail (n > 32)
            const int rem = nn - base;
            const bool ok = el < rem;
            unsigned raw = 0u;
            if (ok) raw = bk[base + el];
            const unsigned q0 = (unsigned)__shfl((int)raw, sb + 0, 64);
            const unsigned q1 = (unsigned)__shfl((int)raw, sb + 1, 64);
            const unsigned q2 = (unsigned)__shfl((int)raw, sb + 2, 64);
            const unsigned q3 = (unsigned)__shfl((int)raw, sb + 3, 64);
            gather_tile(ef, sdst, bw, raw, q0, q1, q2, q3, ok, ebase, srow, el, quad, part);
        }

        // cross-quad reduce, scale by C, deposit row into LDS
        const int lr = (wid << 2) + j;
        float w0 = 0.f, w1 = 0.f;
#pragma unroll
        for (int ct = 0; ct < 8; ++ct) {
            float v = part[ct];
            v += __shfl_xor(v, 16, 64);
            v += __shfl_xor(v, 32, 64);
            v *= Cb;
            if ((ct >> 1) == quad) { if (ct & 1) w1 = v; else w0 = v; }
        }
        const int c0 = (quad << 5) + el;
        cvf[lr * 128 + c0]      = w0;
        cvf[lr * 128 + c0 + 16] = w1;
        hsC[lr * 136 + c0]      = (_Float16)w0;
        hsC[lr * 136 + c0 + 16] = (_Float16)w1;
    }
    __syncthreads();

    // ---------------- phase 2: out6 tail on the block's 16 rows ----------------
    const int ct0 = wid * 2;
    const int rl  = el;
    const int row = nbase + rl;
    const size_t rbase = (size_t)row * H;

    f16x8 bf[4];
    load_bf(hsC, bf, rl, quad);

    f32x4 acc[2], tD[2];

    // L0: hidden of residual-1
    mfma_layerT<2>(w6, bf, ct0, lane, acc);
    store_stripT<2>(hs0, acc, conv_b, ct0, rl, quad);
    __syncthreads();
    load_bf(hs0, bf, rl, quad);

    // L1: t = conv + mlp_out
    mfma_layerT<2>(w6 + 16384, bf, ct0, lane, acc);
#pragma unroll
    for (int ctl = 0; ctl < 2; ++ctl) {
        const int c = (ct0 + ctl) * 16 + quad * 4;
        float4 bb = *(const float4*)(conv_b + H + c);
        float4 cv = *(const float4*)(cvf + rl * 128 + c);
        tD[ctl][0] = cv.x + silu_f(acc[ctl][0] + bb.x);
        tD[ctl][1] = cv.y + silu_f(acc[ctl][1] + bb.y);
        tD[ctl][2] = cv.z + silu_f(acc[ctl][2] + bb.z);
        tD[ctl][3] = cv.w + silu_f(acc[ctl][3] + bb.w);
    }
    store_strip_rawT<2>(hs1, tD, ct0, rl, quad);
    __syncthreads();
    load_bf(hs1, bf, rl, quad);

    // L2: hidden of residual-2
    mfma_layerT<2>(w6 + 2 * 16384, bf, ct0, lane, acc);
    store_stripT<2>(hs0, acc, conv_b + 2 * H, ct0, rl, quad);
    __syncthreads();
    load_bf(hs0, bf, rl, quad);

    // L3: t += mlp_out;  z = t * s2s
    mfma_layerT<2>(w6 + 3 * 16384, bf, ct0, lane, acc);
#pragma unroll
    for (int ctl = 0; ctl < 2; ++ctl) {
        const int c = (ct0 + ctl) * 16 + quad * 4;
        float4 bb = *(const float4*)(conv_b + 3 * H + c);
        float4 sv = *(const float4*)(s2s + rbase + c);
        tD[ctl][0] = (tD[ctl][0] + silu_f(acc[ctl][0] + bb.x)) * sv.x;
        tD[ctl][1] = (tD[ctl][1] + silu_f(acc[ctl][1] + bb.y)) * sv.y;
        tD[ctl][2] = (tD[ctl][2] + silu_f(acc[ctl][2] + bb.z)) * sv.z;
        tD[ctl][3] = (tD[ctl][3] + silu_f(acc[ctl][3] + bb.w)) * sv.w;
    }
    store_strip_rawT<2>(hs1, tD, ct0, rl, quad);
    __syncthreads();
    load_bf(hs1, bf, rl, quad);

    // L4: hidden of final residual
    mfma_layerT<2>(w6 + 4 * 16384, bf, ct0, lane, acc);
    store_stripT<2>(hs0, acc, out_b, ct0, rl, quad);
    __syncthreads();
    load_bf(hs0, bf, rl, quad);

    // L5: out = z + mlp_out
    mfma_layerT<2>(w6 + 5 * 16384, bf, ct0, lane, acc);
#pragma unroll
    for (int ctl = 0; ctl < 2; ++ctl) {
        const int c = (ct0 + ctl) * 16 + quad * 4;
        float4 bb = *(const float4*)(out_b + H + c);
        float4 v;
        v.x = tD[ctl][0] + silu_f(acc[ctl][0] + bb.x);
        v.y = tD[ctl][1] + silu_f(acc[ctl][1] + bb.y);
        v.z = tD[ctl][2] + silu_f(acc[ctl][2] + bb.z);
        v.w = tD[ctl][3] + silu_f(acc[ctl][3] + bb.w);
        *(float4*)(y + rbase + c) = v;
    }
}

// ---------------------------------------------------------------------------
extern "C" void kernel_launch(void* const* d_in, const int* in_sizes, int n_in,
                              void* d_out, int out_size, void* d_ws, size_t ws_size,
                              hipStream_t stream)
{
    const float* scalar = (const float*)d_in[0];
    const float* ef     = (const float*)d_in[1];
    const int*   eidx   = (const int*)d_in[2];
    const float* C      = (const float*)d_in[3];
    const float* emb_w  = (const float*)d_in[4];
    const float* emb_b  = (const float*)d_in[5];
    const float* e_w    = (const float*)d_in[6];
    const float* conv_w = (const float*)d_in[7];
    const float* conv_b = (const float*)d_in[8];
    const float* out_w  = (const float*)d_in[9];
    const float* out_b  = (const float*)d_in[10];

    const int M = 40000;
    const size_t nodeElems = (size_t)M * H;            // 5,120,000

    float* s2s  = (float*)d_ws;
    float* sdst = s2s + nodeElems;
    _Float16* wpk = (_Float16*)(sdst + nodeElems);     // 167936 halves (10 mats + e_w)
    int* cnt    = (int*)(wpk + 167936);                // 40960 * CSTRIDE (padded)
    unsigned* bucket = (unsigned*)(cnt + 40960 * CSTRIDE); // 40960*CAP u32 (~7.9 MB)

    dim3 blk(256);

    pack_w<<<82, blk, 0, stream>>>(emb_w, conv_w, out_w, e_w, wpk, cnt);
    // s2s + scalar_dst + buckets + ef L3-warm, interleaved 2:1
    embscat_k<<<3750, blk, 0, stream>>>(scalar, wpk, emb_b, s2s, sdst,
                                        eidx, cnt, bucket, ef);
    // fused: conv (gather-MFMA) + full out6 tail, hoisted descriptors
    convout_k<<<2500, blk, 0, stream>>>(ef, sdst, wpk + 163840, C, cnt, bucket,
                                        s2s, wpk + 4 * 16384,
                                        conv_b, out_b, (float*)d_out);
}